// Round 1
// baseline (900.399 us; speedup 1.0000x reference)
//
#include <hip/hip_runtime.h>

// GCN 2-layer + edge MLP for SimpleModel_59545426592235.
// Key trick: matmul commutes with the (linear) normalized scatter, so both
// convs scatter only 2-wide aggregates (x*dinv, (h@W2)*dinv) instead of
// 16-wide feature rows: 16M total atomics instead of 51M+.

#define BLK 256

__global__ void k_degree(const int* __restrict__ col, int* __restrict__ deg, int E) {
    int e = blockIdx.x * blockDim.x + threadIdx.x;
    if (e < E) atomicAdd(&deg[col[e]], 1);
}

__global__ void k_node1(const float* __restrict__ x, const int* __restrict__ deg,
                        float* __restrict__ dinv, float2* __restrict__ p,
                        float2* __restrict__ a, int N) {
    int i = blockIdx.x * blockDim.x + threadIdx.x;
    if (i < N) {
        float d = rsqrtf((float)(deg[i] + 1));   // +1 self loop; always > 0
        dinv[i] = d;
        float2 xv = ((const float2*)x)[i];
        float2 pv = make_float2(xv.x * d, xv.y * d);
        p[i] = pv;
        a[i] = pv;   // self-loop contribution: a[c] starts at p[c]
    }
}

__global__ void k_scatter1(const int* __restrict__ row, const int* __restrict__ col,
                           const float2* __restrict__ p, float2* __restrict__ a, int E) {
    int e = blockIdx.x * blockDim.x + threadIdx.x;
    if (e < E) {
        int r = row[e], c = col[e];
        float2 pv = p[r];
        atomicAdd(&a[c].x, pv.x);
        atomicAdd(&a[c].y, pv.y);
    }
}

// h = (dinv*a) @ W1 + b1  -> store h [N,16]
// q = (h @ W2) * dinv     -> store q [N,2], init bacc = q (self-loop term)
__global__ void k_node2(const float* __restrict__ dinv, const float2* __restrict__ a,
                        const float* __restrict__ W1, const float* __restrict__ b1,
                        const float* __restrict__ W2,
                        float* __restrict__ h, float2* __restrict__ q,
                        float2* __restrict__ bacc, int N) {
    __shared__ float sW1[32], sb1[16], sW2[32];
    int t = threadIdx.x;
    if (t < 32) sW1[t] = W1[t];
    else if (t < 64) sW2[t - 32] = W2[t - 32];
    else if (t < 80) sb1[t - 64] = b1[t - 64];
    __syncthreads();
    int i = blockIdx.x * blockDim.x + t;
    if (i < N) {
        float d = dinv[i];
        float2 av = a[i];
        float s0 = d * av.x, s1 = d * av.y;
        float hv[16];
        float hw0 = 0.f, hw1 = 0.f;
        #pragma unroll
        for (int j = 0; j < 16; j++) {
            float v = fmaf(s0, sW1[j], fmaf(s1, sW1[16 + j], sb1[j]));
            hv[j] = v;
            hw0 = fmaf(v, sW2[2 * j], hw0);
            hw1 = fmaf(v, sW2[2 * j + 1], hw1);
        }
        float4* hp = (float4*)(h + 16 * (size_t)i);
        hp[0] = make_float4(hv[0], hv[1], hv[2], hv[3]);
        hp[1] = make_float4(hv[4], hv[5], hv[6], hv[7]);
        hp[2] = make_float4(hv[8], hv[9], hv[10], hv[11]);
        hp[3] = make_float4(hv[12], hv[13], hv[14], hv[15]);
        float2 qv = make_float2(hw0 * d, hw1 * d);
        q[i] = qv;
        bacc[i] = qv;
    }
}

// Fused: scatter2 (bacc[col] += q[row]) + edge MLP + 4-way log_softmax.
__global__ void k_edge(const int* __restrict__ row, const int* __restrict__ col,
                       const float* __restrict__ ea, const float* __restrict__ h,
                       const float2* __restrict__ q, float2* __restrict__ bacc,
                       const float* __restrict__ We, const float* __restrict__ be,
                       float* __restrict__ eout, int E) {
    __shared__ float sWe[132], sbe[4];
    int t = threadIdx.x;
    if (t < 132) sWe[t] = We[t];
    if (t < 4) sbe[t] = be[t];
    __syncthreads();
    int e = blockIdx.x * blockDim.x + t;
    if (e < E) {
        int r = row[e], c = col[e];
        float2 qv = q[r];
        atomicAdd(&bacc[c].x, qv.x);
        atomicAdd(&bacc[c].y, qv.y);

        const float4* hr = (const float4*)(h + 16 * (size_t)r);
        const float4* hc = (const float4*)(h + 16 * (size_t)c);
        float4 r0 = hr[0], r1 = hr[1], r2 = hr[2], r3 = hr[3];
        float4 c0 = hc[0], c1 = hc[1], c2 = hc[2], c3 = hc[3];
        float av = ea[e];

        float acc0 = sbe[0], acc1 = sbe[1], acc2 = sbe[2], acc3 = sbe[3];
        auto mac4 = [&](float hval, int wrow) {
            acc0 = fmaf(hval, sWe[4 * wrow + 0], acc0);
            acc1 = fmaf(hval, sWe[4 * wrow + 1], acc1);
            acc2 = fmaf(hval, sWe[4 * wrow + 2], acc2);
            acc3 = fmaf(hval, sWe[4 * wrow + 3], acc3);
        };
        mac4(r0.x, 0);  mac4(r0.y, 1);  mac4(r0.z, 2);  mac4(r0.w, 3);
        mac4(r1.x, 4);  mac4(r1.y, 5);  mac4(r1.z, 6);  mac4(r1.w, 7);
        mac4(r2.x, 8);  mac4(r2.y, 9);  mac4(r2.z, 10); mac4(r2.w, 11);
        mac4(r3.x, 12); mac4(r3.y, 13); mac4(r3.z, 14); mac4(r3.w, 15);
        mac4(av, 16);
        mac4(c0.x, 17); mac4(c0.y, 18); mac4(c0.z, 19); mac4(c0.w, 20);
        mac4(c1.x, 21); mac4(c1.y, 22); mac4(c1.z, 23); mac4(c1.w, 24);
        mac4(c2.x, 25); mac4(c2.y, 26); mac4(c2.z, 27); mac4(c2.w, 28);
        mac4(c3.x, 29); mac4(c3.y, 30); mac4(c3.z, 31); mac4(c3.w, 32);

        // ReLU
        acc0 = fmaxf(acc0, 0.f); acc1 = fmaxf(acc1, 0.f);
        acc2 = fmaxf(acc2, 0.f); acc3 = fmaxf(acc3, 0.f);
        // log_softmax over 4
        float m = fmaxf(fmaxf(acc0, acc1), fmaxf(acc2, acc3));
        float s = expf(acc0 - m) + expf(acc1 - m) + expf(acc2 - m) + expf(acc3 - m);
        float l = m + logf(s);
        ((float4*)eout)[e] = make_float4(acc0 - l, acc1 - l, acc2 - l, acc3 - l);
    }
}

// out_x = dinv*bacc + b2 -> 2-way log_softmax
__global__ void k_node3(const float* __restrict__ dinv, const float2* __restrict__ bacc,
                        const float* __restrict__ b2, float* __restrict__ out, int N) {
    int i = blockIdx.x * blockDim.x + threadIdx.x;
    if (i < N) {
        float d = dinv[i];
        float2 bv = bacc[i];
        float o0 = fmaf(d, bv.x, b2[0]);
        float o1 = fmaf(d, bv.y, b2[1]);
        float m = fmaxf(o0, o1);
        float l = m + logf(expf(o0 - m) + expf(o1 - m));
        ((float2*)out)[i] = make_float2(o0 - l, o1 - l);
    }
}

extern "C" void kernel_launch(void* const* d_in, const int* in_sizes, int n_in,
                              void* d_out, int out_size, void* d_ws, size_t ws_size,
                              hipStream_t stream) {
    const float* x  = (const float*)d_in[0];
    const int*   ei = (const int*)d_in[1];
    const float* ea = (const float*)d_in[2];
    const float* W1 = (const float*)d_in[3];
    const float* b1 = (const float*)d_in[4];
    const float* We = (const float*)d_in[5];
    const float* be = (const float*)d_in[6];
    const float* W2 = (const float*)d_in[7];
    const float* b2 = (const float*)d_in[8];

    const int N = in_sizes[0] / 2;       // 100000
    const int E = in_sizes[2];           // 3200000 (edge_attr count)
    const int* row = ei;
    const int* col = ei + E;

    float* out_nodes = (float*)d_out;              // [N,2]
    float* out_edges = (float*)d_out + 2 * (size_t)N;  // [E,4]

    // Workspace layout (bytes), all 16B-aligned for N=100000:
    char* ws = (char*)d_ws;
    int*    deg  = (int*)   (ws + 0);          //  N*4  = 400000
    float*  dinv = (float*) (ws + 400000);     //  N*4
    float2* p    = (float2*)(ws + 800000);     //  N*8
    float2* a    = (float2*)(ws + 1600000);    //  N*8
    float*  h    = (float*) (ws + 2400000);    //  N*64 = 6400000
    float2* q    = (float2*)(ws + 8800000);    //  N*8
    float2* bacc = (float2*)(ws + 9600000);    //  N*8  -> total 10400000 B

    int gN = (N + BLK - 1) / BLK;
    int gE = (E + BLK - 1) / BLK;

    hipMemsetAsync(deg, 0, N * sizeof(int), stream);
    k_degree  <<<gE, BLK, 0, stream>>>(col, deg, E);
    k_node1   <<<gN, BLK, 0, stream>>>(x, deg, dinv, p, a, N);
    k_scatter1<<<gE, BLK, 0, stream>>>(row, col, p, a, E);
    k_node2   <<<gN, BLK, 0, stream>>>(dinv, a, W1, b1, W2, h, q, bacc, N);
    k_edge    <<<gE, BLK, 0, stream>>>(row, col, ea, h, q, bacc, We, be, out_edges, E);
    k_node3   <<<gN, BLK, 0, stream>>>(dinv, bacc, b2, out_nodes, N);
}

// Round 2
// 882.756 us; speedup vs baseline: 1.0200x; 1.0200x over previous
//
#include <hip/hip_runtime.h>

// GCN 2-layer + edge MLP for SimpleModel_59545426592235.
// R2: (a) edge-MLP folded into node space: U = h@We[0:16]+be (row side),
//     V = h@We[17:33] (col side) -> per-edge gathers are 32B+16B from
//     L2-resident tables instead of 2x64B from a 6.4MB h table.
//     (b) native fp32 atomics (unsafeAtomicAdd -> global_atomic_add_f32)
//     instead of the default CAS loop.

#define BLK 256

__global__ void k_degree(const int* __restrict__ col, int* __restrict__ deg, int E) {
    int e = blockIdx.x * blockDim.x + threadIdx.x;
    if (e < E) atomicAdd(&deg[col[e]], 1);
}

__global__ void k_node1(const float* __restrict__ x, const int* __restrict__ deg,
                        float* __restrict__ dinv, float2* __restrict__ p,
                        float2* __restrict__ a, int N) {
    int i = blockIdx.x * blockDim.x + threadIdx.x;
    if (i < N) {
        float d = rsqrtf((float)(deg[i] + 1));   // +1 self loop; always > 0
        dinv[i] = d;
        float2 xv = ((const float2*)x)[i];
        float2 pv = make_float2(xv.x * d, xv.y * d);
        p[i] = pv;
        a[i] = pv;   // self-loop contribution
    }
}

__global__ void k_scatter1(const int* __restrict__ row, const int* __restrict__ col,
                           const float2* __restrict__ p, float2* __restrict__ a, int E) {
    int e = blockIdx.x * blockDim.x + threadIdx.x;
    if (e < E) {
        int r = row[e], c = col[e];
        float2 pv = p[r];
        unsafeAtomicAdd(&a[c].x, pv.x);
        unsafeAtomicAdd(&a[c].y, pv.y);
    }
}

// Per node: h = (dinv*a)@W1 + b1 (registers only);
//   rowpack[i] = {U = h@We[0:16] + be, q = (h@W2)*dinv, pad} (8 floats, 32B)
//   V[i]       = h@We[17:33]                              (float4)
//   bacc[i]    = q  (self-loop init)
__global__ void k_node2(const float* __restrict__ dinv, const float2* __restrict__ a,
                        const float* __restrict__ W1, const float* __restrict__ b1,
                        const float* __restrict__ W2, const float* __restrict__ We,
                        const float* __restrict__ be,
                        float* __restrict__ rowpack, float4* __restrict__ V,
                        float2* __restrict__ bacc, int N) {
    __shared__ float sW1[32], sb1[16], sW2[32], sWr[64], sWc[64], sbe[4];
    int t = threadIdx.x;
    if (t < 32) sW1[t] = W1[t];
    else if (t < 64) sW2[t - 32] = W2[t - 32];
    else if (t < 80) sb1[t - 64] = b1[t - 64];
    else if (t < 144) sWr[t - 80] = We[t - 80];          // rows 0..15  ([16,4])
    else if (t < 208) sWc[t - 144] = We[68 + (t - 144)]; // rows 17..32 ([16,4])
    else if (t < 212) sbe[t - 208] = be[t - 208];
    __syncthreads();
    int i = blockIdx.x * blockDim.x + t;
    if (i < N) {
        float d = dinv[i];
        float2 av = a[i];
        float s0 = d * av.x, s1 = d * av.y;
        float u0 = sbe[0], u1 = sbe[1], u2 = sbe[2], u3 = sbe[3];
        float v0 = 0.f, v1 = 0.f, v2 = 0.f, v3 = 0.f;
        float w0 = 0.f, w1 = 0.f;
        #pragma unroll
        for (int j = 0; j < 16; j++) {
            float hj = fmaf(s0, sW1[j], fmaf(s1, sW1[16 + j], sb1[j]));
            u0 = fmaf(hj, sWr[4 * j + 0], u0);
            u1 = fmaf(hj, sWr[4 * j + 1], u1);
            u2 = fmaf(hj, sWr[4 * j + 2], u2);
            u3 = fmaf(hj, sWr[4 * j + 3], u3);
            v0 = fmaf(hj, sWc[4 * j + 0], v0);
            v1 = fmaf(hj, sWc[4 * j + 1], v1);
            v2 = fmaf(hj, sWc[4 * j + 2], v2);
            v3 = fmaf(hj, sWc[4 * j + 3], v3);
            w0 = fmaf(hj, sW2[2 * j], w0);
            w1 = fmaf(hj, sW2[2 * j + 1], w1);
        }
        float4* rp = (float4*)(rowpack + 8 * (size_t)i);
        rp[0] = make_float4(u0, u1, u2, u3);
        float2 qv = make_float2(w0 * d, w1 * d);
        rp[1] = make_float4(qv.x, qv.y, 0.f, 0.f);
        V[i] = make_float4(v0, v1, v2, v3);
        bacc[i] = qv;
    }
}

// Fused: conv2 scatter (bacc[col] += q[row]) + edge MLP + 4-way log_softmax.
__global__ void k_edge(const int* __restrict__ row, const int* __restrict__ col,
                       const float* __restrict__ ea,
                       const float* __restrict__ rowpack, const float4* __restrict__ V,
                       float2* __restrict__ bacc, const float* __restrict__ We,
                       float* __restrict__ eout, int E) {
    __shared__ float sW16[4];
    int t = threadIdx.x;
    if (t < 4) sW16[t] = We[64 + t];   // row 16 of We (edge_attr weights)
    __syncthreads();
    int e = blockIdx.x * blockDim.x + t;
    if (e < E) {
        int r = row[e], c = col[e];
        const float4* rp = (const float4*)(rowpack + 8 * (size_t)r);
        float4 u = rp[0];
        float4 qp = rp[1];
        float4 v = V[c];
        float av = ea[e];
        unsafeAtomicAdd(&bacc[c].x, qp.x);
        unsafeAtomicAdd(&bacc[c].y, qp.y);

        float a0 = u.x + fmaf(av, sW16[0], v.x);
        float a1 = u.y + fmaf(av, sW16[1], v.y);
        float a2 = u.z + fmaf(av, sW16[2], v.z);
        float a3 = u.w + fmaf(av, sW16[3], v.w);
        a0 = fmaxf(a0, 0.f); a1 = fmaxf(a1, 0.f);
        a2 = fmaxf(a2, 0.f); a3 = fmaxf(a3, 0.f);
        float m = fmaxf(fmaxf(a0, a1), fmaxf(a2, a3));
        float s = expf(a0 - m) + expf(a1 - m) + expf(a2 - m) + expf(a3 - m);
        float l = m + logf(s);
        ((float4*)eout)[e] = make_float4(a0 - l, a1 - l, a2 - l, a3 - l);
    }
}

// out_x = dinv*bacc + b2 -> 2-way log_softmax
__global__ void k_node3(const float* __restrict__ dinv, const float2* __restrict__ bacc,
                        const float* __restrict__ b2, float* __restrict__ out, int N) {
    int i = blockIdx.x * blockDim.x + threadIdx.x;
    if (i < N) {
        float d = dinv[i];
        float2 bv = bacc[i];
        float o0 = fmaf(d, bv.x, b2[0]);
        float o1 = fmaf(d, bv.y, b2[1]);
        float m = fmaxf(o0, o1);
        float l = m + logf(expf(o0 - m) + expf(o1 - m));
        ((float2*)out)[i] = make_float2(o0 - l, o1 - l);
    }
}

extern "C" void kernel_launch(void* const* d_in, const int* in_sizes, int n_in,
                              void* d_out, int out_size, void* d_ws, size_t ws_size,
                              hipStream_t stream) {
    const float* x  = (const float*)d_in[0];
    const int*   ei = (const int*)d_in[1];
    const float* ea = (const float*)d_in[2];
    const float* W1 = (const float*)d_in[3];
    const float* b1 = (const float*)d_in[4];
    const float* We = (const float*)d_in[5];
    const float* be = (const float*)d_in[6];
    const float* W2 = (const float*)d_in[7];
    const float* b2 = (const float*)d_in[8];

    const int N = in_sizes[0] / 2;       // 100000
    const int E = in_sizes[2];           // 3200000
    const int* row = ei;
    const int* col = ei + E;

    float* out_nodes = (float*)d_out;                  // [N,2]
    float* out_edges = (float*)d_out + 2 * (size_t)N;  // [E,4]

    // Workspace layout (bytes, all 16B-aligned for N=100000):
    char* ws = (char*)d_ws;
    int*    deg  = (int*)   (ws + 0);          // N*4  = 400000
    float*  dinv = (float*) (ws + 400000);     // N*4
    float2* p    = (float2*)(ws + 800000);     // N*8
    float2* a    = (float2*)(ws + 1600000);    // N*8
    float*  rpk  = (float*) (ws + 2400000);    // N*32 = 3200000
    float4* V    = (float4*)(ws + 5600000);    // N*16 = 1600000
    float2* bacc = (float2*)(ws + 7200000);    // N*8  -> total 8000000 B

    int gN = (N + BLK - 1) / BLK;
    int gE = (E + BLK - 1) / BLK;

    hipMemsetAsync(deg, 0, N * sizeof(int), stream);
    k_degree  <<<gE, BLK, 0, stream>>>(col, deg, E);
    k_node1   <<<gN, BLK, 0, stream>>>(x, deg, dinv, p, a, N);
    k_scatter1<<<gE, BLK, 0, stream>>>(row, col, p, a, E);
    k_node2   <<<gN, BLK, 0, stream>>>(dinv, a, W1, b1, W2, We, be, rpk, V, bacc, N);
    k_edge    <<<gE, BLK, 0, stream>>>(row, col, ea, rpk, V, bacc, We, out_edges, E);
    k_node3   <<<gN, BLK, 0, stream>>>(dinv, bacc, b2, out_nodes, N);
}

// Round 3
// 866.507 us; speedup vs baseline: 1.0391x; 1.0188x over previous
//
#include <hip/hip_runtime.h>

// GCN 2-layer + edge MLP for SimpleModel_59545426592235.
// R3: R-way replicated atomic accumulators (deg, a, bacc). Device-scope fp32
// atomics execute at the memory-side coherent point (per-XCD L2s are not
// coherent); with 100k nodes / 6.4M adds each 64B line got ~256 serialized
// ops -> 330us scatter. Replication divides per-line/per-address contention
// by R; cheap streaming reduces fold the copies (+ self-loop terms).

#define BLK 256
#define RMAX 16

__global__ void k_degree(const int* __restrict__ col, int* __restrict__ deg,
                         int N, int E, int R) {
    int e = blockIdx.x * blockDim.x + threadIdx.x;
    if (e < E) {
        int* d = deg + (size_t)(blockIdx.x % R) * N;
        atomicAdd(&d[col[e]], 1);
    }
}

// reduce deg copies (+1 self loop) -> dinv; p = x * dinv
__global__ void k_node1(const float* __restrict__ x, const int* __restrict__ deg,
                        float* __restrict__ dinv, float2* __restrict__ p,
                        int N, int R) {
    int i = blockIdx.x * blockDim.x + threadIdx.x;
    if (i < N) {
        int dsum = 1;
        for (int r = 0; r < R; r++) dsum += deg[(size_t)r * N + i];
        float d = rsqrtf((float)dsum);
        dinv[i] = d;
        float2 xv = ((const float2*)x)[i];
        p[i] = make_float2(xv.x * d, xv.y * d);
    }
}

__global__ void k_scatter1(const int* __restrict__ row, const int* __restrict__ col,
                           const float2* __restrict__ p, float2* __restrict__ a,
                           int N, int E, int R) {
    int e = blockIdx.x * blockDim.x + threadIdx.x;
    if (e < E) {
        float2* ac = a + (size_t)(blockIdx.x % R) * N;
        int r = row[e], c = col[e];
        float2 pv = p[r];
        unsafeAtomicAdd(&ac[c].x, pv.x);
        unsafeAtomicAdd(&ac[c].y, pv.y);
    }
}

// Reduce a copies (+ self-loop p[i]); h = (dinv*a)@W1+b1 in registers;
// rowpack[i] = {U = h@We[0:16]+be, q = (h@W2)*dinv, pad} (32B); V[i] = h@We[17:33].
__global__ void k_node2(const float* __restrict__ dinv, const float2* __restrict__ p,
                        const float2* __restrict__ a,
                        const float* __restrict__ W1, const float* __restrict__ b1,
                        const float* __restrict__ W2, const float* __restrict__ We,
                        const float* __restrict__ be,
                        float* __restrict__ rowpack, float4* __restrict__ V,
                        int N, int R) {
    __shared__ float sW1[32], sb1[16], sW2[32], sWr[64], sWc[64], sbe[4];
    int t = threadIdx.x;
    if (t < 32) sW1[t] = W1[t];
    else if (t < 64) sW2[t - 32] = W2[t - 32];
    else if (t < 80) sb1[t - 64] = b1[t - 64];
    else if (t < 144) sWr[t - 80] = We[t - 80];          // rows 0..15
    else if (t < 208) sWc[t - 144] = We[68 + (t - 144)]; // rows 17..32
    else if (t < 212) sbe[t - 208] = be[t - 208];
    __syncthreads();
    int i = blockIdx.x * blockDim.x + t;
    if (i < N) {
        float d = dinv[i];
        float2 av = p[i];   // self-loop contribution
        for (int r = 0; r < R; r++) {
            float2 c = a[(size_t)r * N + i];
            av.x += c.x; av.y += c.y;
        }
        float s0 = d * av.x, s1 = d * av.y;
        float u0 = sbe[0], u1 = sbe[1], u2 = sbe[2], u3 = sbe[3];
        float v0 = 0.f, v1 = 0.f, v2 = 0.f, v3 = 0.f;
        float w0 = 0.f, w1 = 0.f;
        #pragma unroll
        for (int j = 0; j < 16; j++) {
            float hj = fmaf(s0, sW1[j], fmaf(s1, sW1[16 + j], sb1[j]));
            u0 = fmaf(hj, sWr[4 * j + 0], u0);
            u1 = fmaf(hj, sWr[4 * j + 1], u1);
            u2 = fmaf(hj, sWr[4 * j + 2], u2);
            u3 = fmaf(hj, sWr[4 * j + 3], u3);
            v0 = fmaf(hj, sWc[4 * j + 0], v0);
            v1 = fmaf(hj, sWc[4 * j + 1], v1);
            v2 = fmaf(hj, sWc[4 * j + 2], v2);
            v3 = fmaf(hj, sWc[4 * j + 3], v3);
            w0 = fmaf(hj, sW2[2 * j], w0);
            w1 = fmaf(hj, sW2[2 * j + 1], w1);
        }
        float4* rp = (float4*)(rowpack + 8 * (size_t)i);
        rp[0] = make_float4(u0, u1, u2, u3);
        rp[1] = make_float4(w0 * d, w1 * d, 0.f, 0.f);  // q
        V[i] = make_float4(v0, v1, v2, v3);
    }
}

// Fused: conv2 scatter (bacc_copy[col] += q[row]) + edge MLP + log_softmax(4).
__global__ void k_edge(const int* __restrict__ row, const int* __restrict__ col,
                       const float* __restrict__ ea,
                       const float* __restrict__ rowpack, const float4* __restrict__ V,
                       float2* __restrict__ bacc, const float* __restrict__ We,
                       float* __restrict__ eout, int N, int E, int R) {
    __shared__ float sW16[4];
    int t = threadIdx.x;
    if (t < 4) sW16[t] = We[64 + t];   // edge_attr weight row
    __syncthreads();
    int e = blockIdx.x * blockDim.x + t;
    if (e < E) {
        float2* bc = bacc + (size_t)(blockIdx.x % R) * N;
        int r = row[e], c = col[e];
        const float4* rp = (const float4*)(rowpack + 8 * (size_t)r);
        float4 u = rp[0];
        float4 qp = rp[1];
        float4 v = V[c];
        float av = ea[e];
        unsafeAtomicAdd(&bc[c].x, qp.x);
        unsafeAtomicAdd(&bc[c].y, qp.y);

        float a0 = u.x + fmaf(av, sW16[0], v.x);
        float a1 = u.y + fmaf(av, sW16[1], v.y);
        float a2 = u.z + fmaf(av, sW16[2], v.z);
        float a3 = u.w + fmaf(av, sW16[3], v.w);
        a0 = fmaxf(a0, 0.f); a1 = fmaxf(a1, 0.f);
        a2 = fmaxf(a2, 0.f); a3 = fmaxf(a3, 0.f);
        float m = fmaxf(fmaxf(a0, a1), fmaxf(a2, a3));
        float s = expf(a0 - m) + expf(a1 - m) + expf(a2 - m) + expf(a3 - m);
        float l = m + logf(s);
        ((float4*)eout)[e] = make_float4(a0 - l, a1 - l, a2 - l, a3 - l);
    }
}

// Reduce bacc copies (+ self-loop q[i]); out = dinv*b + b2 -> log_softmax(2).
__global__ void k_node3(const float* __restrict__ dinv, const float* __restrict__ rowpack,
                        const float2* __restrict__ bacc, const float* __restrict__ b2,
                        float* __restrict__ out, int N, int R) {
    int i = blockIdx.x * blockDim.x + threadIdx.x;
    if (i < N) {
        const float4* rp = (const float4*)(rowpack + 8 * (size_t)i);
        float4 qp = rp[1];
        float bx = qp.x, by = qp.y;   // self-loop contribution
        for (int r = 0; r < R; r++) {
            float2 c = bacc[(size_t)r * N + i];
            bx += c.x; by += c.y;
        }
        float d = dinv[i];
        float o0 = fmaf(d, bx, b2[0]);
        float o1 = fmaf(d, by, b2[1]);
        float m = fmaxf(o0, o1);
        float l = m + logf(expf(o0 - m) + expf(o1 - m));
        ((float2*)out)[i] = make_float2(o0 - l, o1 - l);
    }
}

extern "C" void kernel_launch(void* const* d_in, const int* in_sizes, int n_in,
                              void* d_out, int out_size, void* d_ws, size_t ws_size,
                              hipStream_t stream) {
    const float* x  = (const float*)d_in[0];
    const int*   ei = (const int*)d_in[1];
    const float* ea = (const float*)d_in[2];
    const float* W1 = (const float*)d_in[3];
    const float* b1 = (const float*)d_in[4];
    const float* We = (const float*)d_in[5];
    const float* be = (const float*)d_in[6];
    const float* W2 = (const float*)d_in[7];
    const float* b2 = (const float*)d_in[8];

    const int N = in_sizes[0] / 2;       // 100000
    const int E = in_sizes[2];           // 3200000
    const int* row = ei;
    const int* col = ei + E;

    float* out_nodes = (float*)d_out;                  // [N,2]
    float* out_edges = (float*)d_out + 2 * (size_t)N;  // [E,4]

    // Workspace layout (bytes, 16B-aligned; N=100000):
    //   dinv  N*4        @ 0
    //   p     N*8        @ 400000
    //   rpk   N*32       @ 1200000
    //   V     N*16       @ 4400000
    //   deg   R*N*4      @ 6000000
    //   a     R*N*8      @ 6000000 + R*400000
    //   bacc  R*N*8      @ 6000000 + R*1200000
    const size_t base = 6000000;
    const size_t perR = 2000000;  // N*(4+8+8)
    int R = 1;
    if (ws_size > base + perR) {
        size_t r = (ws_size - base) / perR;
        R = (int)(r < RMAX ? r : RMAX);
        if (R < 1) R = 1;
    }

    char* ws = (char*)d_ws;
    float*  dinv = (float*) (ws + 0);
    float2* p    = (float2*)(ws + 400000);
    float*  rpk  = (float*) (ws + 1200000);
    float4* V    = (float4*)(ws + 4400000);
    int*    deg  = (int*)   (ws + base);
    float2* a    = (float2*)(ws + base + (size_t)R * 400000);
    float2* bacc = (float2*)(ws + base + (size_t)R * 1200000);

    int gN = (N + BLK - 1) / BLK;
    int gE = (E + BLK - 1) / BLK;

    hipMemsetAsync(deg, 0, (size_t)R * perR, stream);  // zeros deg, a, bacc
    k_degree  <<<gE, BLK, 0, stream>>>(col, deg, N, E, R);
    k_node1   <<<gN, BLK, 0, stream>>>(x, deg, dinv, p, N, R);
    k_scatter1<<<gE, BLK, 0, stream>>>(row, col, p, a, N, E, R);
    k_node2   <<<gN, BLK, 0, stream>>>(dinv, p, a, W1, b1, W2, We, be, rpk, V, N, R);
    k_edge    <<<gE, BLK, 0, stream>>>(row, col, ea, rpk, V, bacc, We, out_edges, N, E, R);
    k_node3   <<<gN, BLK, 0, stream>>>(dinv, rpk, bacc, b2, out_nodes, N, R);
}

// Round 4
// 728.522 us; speedup vs baseline: 1.2359x; 1.1894x over previous
//
#include <hip/hip_runtime.h>

// GCN 2-layer + edge MLP for SimpleModel_59545426592235.
// R4: XCD-local atomics. Device-scope (agent) atomics carry sc1 and are
// forwarded past the per-XCD L2 to the memory-side coherent point -> ~20
// ops/ns device-wide, which WAS the entire 866us runtime (16M atomic ops).
// Fix: 8 accumulator copies, one per physical XCD (indexed by
// s_getreg(HW_REG_XCC_ID)), updated with WORKGROUP-scope atomics (no sc1 ->
// RMW executes in the local TCC/L2 at L2 throughput; atomicity holds for all
// requesters sharing that TCC). End-of-kernel L2 writeback publishes the
// copies to the reduce kernels. Int32 fixed point (2^21 / 2^22 scales)
// guarantees native atomic lowering (no fp CAS-loop risk); quantization
// error ~1e-5 << 0.043 threshold.

#define BLK 256
#define NXCD 8
#define S1 2097152.0f    // 2^21  conv1 scatter scale
#define S2 4194304.0f    // 2^22  conv2 scatter scale

__device__ __forceinline__ int xcd_id() {
    // HW_REG_XCC_ID = 20, offset 0, width 4
    return __builtin_amdgcn_s_getreg(20 | (3 << 11)) & (NXCD - 1);
}

template <bool LOCAL>
__device__ __forceinline__ void atom_add(int* p, int v) {
    if (LOCAL)
        __hip_atomic_fetch_add(p, v, __ATOMIC_RELAXED, __HIP_MEMORY_SCOPE_WORKGROUP);
    else
        __hip_atomic_fetch_add(p, v, __ATOMIC_RELAXED, __HIP_MEMORY_SCOPE_AGENT);
}

template <bool LOCAL>
__global__ void k_degree(const int* __restrict__ col, int* __restrict__ deg,
                         int N, int E) {
    int e = blockIdx.x * blockDim.x + threadIdx.x;
    if (e < E) {
        int* d = deg + (size_t)(LOCAL ? xcd_id() : 0) * N;
        atom_add<LOCAL>(&d[col[e]], 1);
    }
}

// reduce deg copies (+1 self loop) -> dinv; p = x * dinv
__global__ void k_node1(const float* __restrict__ x, const int* __restrict__ deg,
                        float* __restrict__ dinv, float2* __restrict__ p,
                        int N, int R) {
    int i = blockIdx.x * blockDim.x + threadIdx.x;
    if (i < N) {
        int dsum = 1;
        for (int r = 0; r < R; r++) dsum += deg[(size_t)r * N + i];
        float d = rsqrtf((float)dsum);
        dinv[i] = d;
        float2 xv = ((const float2*)x)[i];
        p[i] = make_float2(xv.x * d, xv.y * d);
    }
}

template <bool LOCAL>
__global__ void k_scatter1(const int* __restrict__ row, const int* __restrict__ col,
                           const float2* __restrict__ p, int2* __restrict__ aint,
                           int N, int E) {
    int e = blockIdx.x * blockDim.x + threadIdx.x;
    if (e < E) {
        int2* ac = aint + (size_t)(LOCAL ? xcd_id() : 0) * N;
        int r = row[e], c = col[e];
        float2 pv = p[r];
        int ix = __float2int_rn(pv.x * S1);
        int iy = __float2int_rn(pv.y * S1);
        atom_add<LOCAL>(&ac[c].x, ix);
        atom_add<LOCAL>(&ac[c].y, iy);
    }
}

// Reduce aint copies (+ self-loop p[i]); h = (dinv*a)@W1+b1 in registers;
// rowpack[i] = {U = h@We[0:16]+be (4f), q (2f), qi fixed-point (2i as float bits)}
// V[i] = h@We[17:33].
__global__ void k_node2(const float* __restrict__ dinv, const float2* __restrict__ p,
                        const int2* __restrict__ aint,
                        const float* __restrict__ W1, const float* __restrict__ b1,
                        const float* __restrict__ W2, const float* __restrict__ We,
                        const float* __restrict__ be,
                        float* __restrict__ rowpack, float4* __restrict__ V,
                        int N, int R) {
    __shared__ float sW1[32], sb1[16], sW2[32], sWr[64], sWc[64], sbe[4];
    int t = threadIdx.x;
    if (t < 32) sW1[t] = W1[t];
    else if (t < 64) sW2[t - 32] = W2[t - 32];
    else if (t < 80) sb1[t - 64] = b1[t - 64];
    else if (t < 144) sWr[t - 80] = We[t - 80];          // rows 0..15
    else if (t < 208) sWc[t - 144] = We[68 + (t - 144)]; // rows 17..32
    else if (t < 212) sbe[t - 208] = be[t - 208];
    __syncthreads();
    int i = blockIdx.x * blockDim.x + t;
    if (i < N) {
        float d = dinv[i];
        long long sx = 0, sy = 0;
        for (int r = 0; r < R; r++) {
            int2 c = aint[(size_t)r * N + i];
            sx += c.x; sy += c.y;
        }
        float2 av = p[i];  // self-loop (exact float)
        av.x += (float)sx * (1.0f / S1);
        av.y += (float)sy * (1.0f / S1);
        float s0 = d * av.x, s1 = d * av.y;
        float u0 = sbe[0], u1 = sbe[1], u2 = sbe[2], u3 = sbe[3];
        float v0 = 0.f, v1 = 0.f, v2 = 0.f, v3 = 0.f;
        float w0 = 0.f, w1 = 0.f;
        #pragma unroll
        for (int j = 0; j < 16; j++) {
            float hj = fmaf(s0, sW1[j], fmaf(s1, sW1[16 + j], sb1[j]));
            u0 = fmaf(hj, sWr[4 * j + 0], u0);
            u1 = fmaf(hj, sWr[4 * j + 1], u1);
            u2 = fmaf(hj, sWr[4 * j + 2], u2);
            u3 = fmaf(hj, sWr[4 * j + 3], u3);
            v0 = fmaf(hj, sWc[4 * j + 0], v0);
            v1 = fmaf(hj, sWc[4 * j + 1], v1);
            v2 = fmaf(hj, sWc[4 * j + 2], v2);
            v3 = fmaf(hj, sWc[4 * j + 3], v3);
            w0 = fmaf(hj, sW2[2 * j], w0);
            w1 = fmaf(hj, sW2[2 * j + 1], w1);
        }
        float qx = w0 * d, qy = w1 * d;
        float4* rp = (float4*)(rowpack + 8 * (size_t)i);
        rp[0] = make_float4(u0, u1, u2, u3);
        rp[1] = make_float4(qx, qy,
                            __int_as_float(__float2int_rn(qx * S2)),
                            __int_as_float(__float2int_rn(qy * S2)));
        V[i] = make_float4(v0, v1, v2, v3);
    }
}

// Fused: conv2 scatter (bint_copy[col] += qi[row]) + edge MLP + log_softmax(4).
template <bool LOCAL>
__global__ void k_edge(const int* __restrict__ row, const int* __restrict__ col,
                       const float* __restrict__ ea,
                       const float* __restrict__ rowpack, const float4* __restrict__ V,
                       int2* __restrict__ bint, const float* __restrict__ We,
                       float* __restrict__ eout, int N, int E) {
    __shared__ float sW16[4];
    int t = threadIdx.x;
    if (t < 4) sW16[t] = We[64 + t];   // edge_attr weight row
    __syncthreads();
    int e = blockIdx.x * blockDim.x + t;
    if (e < E) {
        int2* bc = bint + (size_t)(LOCAL ? xcd_id() : 0) * N;
        int r = row[e], c = col[e];
        const float4* rp = (const float4*)(rowpack + 8 * (size_t)r);
        float4 u = rp[0];
        float4 qp = rp[1];
        float4 v = V[c];
        float av = ea[e];
        atom_add<LOCAL>(&bc[c].x, __float_as_int(qp.z));
        atom_add<LOCAL>(&bc[c].y, __float_as_int(qp.w));

        float a0 = u.x + fmaf(av, sW16[0], v.x);
        float a1 = u.y + fmaf(av, sW16[1], v.y);
        float a2 = u.z + fmaf(av, sW16[2], v.z);
        float a3 = u.w + fmaf(av, sW16[3], v.w);
        a0 = fmaxf(a0, 0.f); a1 = fmaxf(a1, 0.f);
        a2 = fmaxf(a2, 0.f); a3 = fmaxf(a3, 0.f);
        float m = fmaxf(fmaxf(a0, a1), fmaxf(a2, a3));
        float s = expf(a0 - m) + expf(a1 - m) + expf(a2 - m) + expf(a3 - m);
        float l = m + logf(s);
        ((float4*)eout)[e] = make_float4(a0 - l, a1 - l, a2 - l, a3 - l);
    }
}

// Reduce bint copies (+ self-loop q); out = dinv*b + b2 -> log_softmax(2).
__global__ void k_node3(const float* __restrict__ dinv, const float* __restrict__ rowpack,
                        const int2* __restrict__ bint, const float* __restrict__ b2,
                        float* __restrict__ out, int N, int R) {
    int i = blockIdx.x * blockDim.x + threadIdx.x;
    if (i < N) {
        const float4* rp = (const float4*)(rowpack + 8 * (size_t)i);
        float4 qp = rp[1];
        long long sx = 0, sy = 0;
        for (int r = 0; r < R; r++) {
            int2 c = bint[(size_t)r * N + i];
            sx += c.x; sy += c.y;
        }
        float bx = qp.x + (float)sx * (1.0f / S2);
        float by = qp.y + (float)sy * (1.0f / S2);
        float d = dinv[i];
        float o0 = fmaf(d, bx, b2[0]);
        float o1 = fmaf(d, by, b2[1]);
        float m = fmaxf(o0, o1);
        float l = m + logf(expf(o0 - m) + expf(o1 - m));
        ((float2*)out)[i] = make_float2(o0 - l, o1 - l);
    }
}

extern "C" void kernel_launch(void* const* d_in, const int* in_sizes, int n_in,
                              void* d_out, int out_size, void* d_ws, size_t ws_size,
                              hipStream_t stream) {
    const float* x  = (const float*)d_in[0];
    const int*   ei = (const int*)d_in[1];
    const float* ea = (const float*)d_in[2];
    const float* W1 = (const float*)d_in[3];
    const float* b1 = (const float*)d_in[4];
    const float* We = (const float*)d_in[5];
    const float* be = (const float*)d_in[6];
    const float* W2 = (const float*)d_in[7];
    const float* b2 = (const float*)d_in[8];

    const int N = in_sizes[0] / 2;       // 100000
    const int E = in_sizes[2];           // 3200000
    const int* row = ei;
    const int* col = ei + E;

    float* out_nodes = (float*)d_out;                  // [N,2]
    float* out_edges = (float*)d_out + 2 * (size_t)N;  // [E,4]

    // Workspace layout (bytes, N=100000):
    //   dinv N*4 @0 | p N*8 @400000 | rpk N*32 @1200000 | V N*16 @4400000
    //   zero-region @6000000: deg R*N*4, aint R*N*8, bint R*N*8
    const size_t Z = 6000000;
    const size_t needL = Z + (size_t)NXCD * 100000 * 20;  // 22 MB for R=8
    bool local = (ws_size >= needL);
    int R = local ? NXCD : 1;

    char* ws = (char*)d_ws;
    float*  dinv = (float*) (ws + 0);
    float2* p    = (float2*)(ws + 400000);
    float*  rpk  = (float*) (ws + 1200000);
    float4* V    = (float4*)(ws + 4400000);
    int*    deg  = (int*)   (ws + Z);
    int2*   aint = (int2*)  (ws + Z + (size_t)R * N * 4);
    int2*   bint = (int2*)  (ws + Z + (size_t)R * N * 12);

    int gN = (N + BLK - 1) / BLK;
    int gE = (E + BLK - 1) / BLK;

    hipMemsetAsync(deg, 0, (size_t)R * N * 20, stream);  // zeros deg, aint, bint
    if (local) {
        k_degree<true>  <<<gE, BLK, 0, stream>>>(col, deg, N, E);
        k_node1         <<<gN, BLK, 0, stream>>>(x, deg, dinv, p, N, R);
        k_scatter1<true><<<gE, BLK, 0, stream>>>(row, col, p, aint, N, E);
        k_node2         <<<gN, BLK, 0, stream>>>(dinv, p, aint, W1, b1, W2, We, be, rpk, V, N, R);
        k_edge<true>    <<<gE, BLK, 0, stream>>>(row, col, ea, rpk, V, bint, We, out_edges, N, E);
        k_node3         <<<gN, BLK, 0, stream>>>(dinv, rpk, bint, b2, out_nodes, N, R);
    } else {
        k_degree<false>  <<<gE, BLK, 0, stream>>>(col, deg, N, E);
        k_node1          <<<gN, BLK, 0, stream>>>(x, deg, dinv, p, N, R);
        k_scatter1<false><<<gE, BLK, 0, stream>>>(row, col, p, aint, N, E);
        k_node2          <<<gN, BLK, 0, stream>>>(dinv, p, aint, W1, b1, W2, We, be, rpk, V, N, R);
        k_edge<false>    <<<gE, BLK, 0, stream>>>(row, col, ea, rpk, V, bint, We, out_edges, N, E);
        k_node3          <<<gN, BLK, 0, stream>>>(dinv, rpk, bint, b2, out_nodes, N, R);
    }
}

// Round 5
// 260.933 us; speedup vs baseline: 3.4507x; 2.7920x over previous
//
#include <hip/hip_runtime.h>

// GCN 2-layer + edge MLP for SimpleModel_59545426592235.
// R5: eliminate per-edge global atomics (measured hard limit ~25 G atomic
// ops/s device-wide; 16M atomics == the entire 729us). Counting-sort edges
// into 128-node buckets (one workgroup per bucket), then degree/conv1/conv2
// aggregate with LDS atomics only. Remaining global atomics: ~0.6M
// (per-block-per-bucket histogram flush + cursor reservation).
// Int fixed point (2^21 / 2^19) -> native LDS adds, deterministic output.

#define BLK 256
#define CH 8192            // edges per partition chunk
#define BSH 7              // 128 nodes per bucket
#define BSZ 128
#define NBMAX 1024         // max buckets (N <= 131072)
#define S1 2097152.0f      // 2^21 conv1 scale
#define S2 524288.0f       // 2^19 conv2 scale

// ---- per-chunk LDS histogram of col buckets -> global bucket counts
__global__ void k_hist(const int* __restrict__ col, int* __restrict__ gcount,
                       int E, int NB) {
    __shared__ int hist[NBMAX];
    int t = threadIdx.x;
    for (int b = t; b < NB; b += BLK) hist[b] = 0;
    __syncthreads();
    int e0 = blockIdx.x * CH;
    int cnt = min(CH, E - e0);
    for (int k = t; k < cnt; k += BLK)
        atomicAdd(&hist[col[e0 + k] >> BSH], 1);
    __syncthreads();
    for (int b = t; b < NB; b += BLK) {
        int h = hist[b];
        if (h) atomicAdd(&gcount[b], h);
    }
}

// ---- exclusive scan of bucket counts -> gbase[NB+1]; gcursor = gbase
__global__ void k_scan(const int* __restrict__ gcount, int* __restrict__ gbase,
                       int* __restrict__ gcursor, int NB) {
    __shared__ int sa[NBMAX], sb[NBMAX];
    int t = threadIdx.x;
    for (int i = t; i < NBMAX; i += BLK) sa[i] = (i < NB) ? gcount[i] : 0;
    __syncthreads();
    int *src = sa, *dst = sb;
    for (int off = 1; off < NBMAX; off <<= 1) {
        for (int i = t; i < NBMAX; i += BLK)
            dst[i] = src[i] + ((i >= off) ? src[i - off] : 0);
        __syncthreads();
        int* tmp = src; src = dst; dst = tmp;
    }
    for (int i = t; i < NB; i += BLK) {
        int ex = src[i] - gcount[i];
        gbase[i] = ex;
        gcursor[i] = ex;
    }
    if (t == 0) gbase[NB] = src[NB - 1];
}

// ---- partition: LDS counting sort of each chunk, coalesced run flush
__global__ void k_part(const int* __restrict__ row, const int* __restrict__ col,
                       int* __restrict__ gcursor, unsigned* __restrict__ part,
                       int E, int NB) {
    __shared__ int sa[NBMAX], sb[NBMAX];
    __shared__ int hist[NBMAX], lstart[NBMAX], lcur[NBMAX], gb[NBMAX];
    __shared__ unsigned sbuf[CH];
    int t = threadIdx.x;
    int e0 = blockIdx.x * CH;
    int cnt = min(CH, E - e0);
    for (int b = t; b < NB; b += BLK) hist[b] = 0;
    __syncthreads();
    for (int k = t; k < cnt; k += BLK)
        atomicAdd(&hist[col[e0 + k] >> BSH], 1);
    __syncthreads();
    // exclusive scan hist -> lstart; init lcur; reserve global space
    for (int i = t; i < NBMAX; i += BLK) sa[i] = (i < NB) ? hist[i] : 0;
    __syncthreads();
    int *src = sa, *dst = sb;
    for (int off = 1; off < NBMAX; off <<= 1) {
        for (int i = t; i < NBMAX; i += BLK)
            dst[i] = src[i] + ((i >= off) ? src[i - off] : 0);
        __syncthreads();
        int* tmp = src; src = dst; dst = tmp;
    }
    for (int i = t; i < NB; i += BLK) {
        int h = hist[i];
        int ex = src[i] - h;
        lstart[i] = ex;
        lcur[i] = ex;
        gb[i] = h ? atomicAdd(&gcursor[i], h) : 0;
    }
    __syncthreads();
    // place chunk edges into LDS buffer grouped by bucket
    for (int k = t; k < cnt; k += BLK) {
        int e = e0 + k;
        int c = col[e], r = row[e];
        int b = c >> BSH;
        int off = atomicAdd(&lcur[b], 1);
        sbuf[off] = ((unsigned)r << BSH) | (unsigned)(c & (BSZ - 1));
    }
    __syncthreads();
    // flush: output position j belongs to bucket = last b with lstart[b] <= j
    for (int j = t; j < cnt; j += BLK) {
        int lo = 0, hi = NB - 1;
        while (lo < hi) {
            int mid = (lo + hi + 1) >> 1;
            if (lstart[mid] <= j) lo = mid; else hi = mid - 1;
        }
        part[gb[lo] + (j - lstart[lo])] = sbuf[j];
    }
}

// ---- per-bucket degree count -> dinv, pi = x * dinv (fixed point)
__global__ void k_nodeA(const unsigned* __restrict__ part, const int* __restrict__ gbase,
                        const float2* __restrict__ x2, float* __restrict__ dinv,
                        int2* __restrict__ pi, int N) {
    __shared__ int cnt[BSZ];
    int t = threadIdx.x;
    if (t < BSZ) cnt[t] = 0;
    __syncthreads();
    int b = blockIdx.x;
    int j0 = gbase[b], j1 = gbase[b + 1];
    for (int j = j0 + t; j < j1; j += BLK)
        atomicAdd(&cnt[part[j] & (BSZ - 1)], 1);
    __syncthreads();
    if (t < BSZ) {
        int node = (b << BSH) + t;
        if (node < N) {
            float d = rsqrtf((float)(cnt[t] + 1));   // +1 self loop
            dinv[node] = d;
            float2 xv = x2[node];
            pi[node] = make_int2(__float2int_rn(xv.x * d * S1),
                                 __float2int_rn(xv.y * d * S1));
        }
    }
}

// ---- per-bucket conv1 aggregate (LDS int) -> h -> U, V, qi
__global__ void k_nodeB(const unsigned* __restrict__ part, const int* __restrict__ gbase,
                        const float* __restrict__ dinv, const int2* __restrict__ pi,
                        const float* __restrict__ W1, const float* __restrict__ b1,
                        const float* __restrict__ W2, const float* __restrict__ We,
                        const float* __restrict__ be,
                        float4* __restrict__ U, float4* __restrict__ V,
                        int2* __restrict__ qi, int N) {
    __shared__ int accx[BSZ], accy[BSZ];
    __shared__ float sW1[32], sb1[16], sW2[32], sWr[64], sWc[64], sbe[4];
    int t = threadIdx.x;
    if (t < BSZ) { accx[t] = 0; accy[t] = 0; }
    if (t < 32) sW1[t] = W1[t];
    else if (t < 64) sW2[t - 32] = W2[t - 32];
    else if (t < 80) sb1[t - 64] = b1[t - 64];
    else if (t < 144) sWr[t - 80] = We[t - 80];          // We rows 0..15
    else if (t < 208) sWc[t - 144] = We[68 + (t - 144)]; // We rows 17..32
    else if (t < 212) sbe[t - 208] = be[t - 208];
    __syncthreads();
    int b = blockIdx.x;
    int j0 = gbase[b], j1 = gbase[b + 1];
    for (int j = j0 + t; j < j1; j += BLK) {
        unsigned w = part[j];
        int2 pv = pi[w >> BSH];
        int l = (int)(w & (BSZ - 1));
        atomicAdd(&accx[l], pv.x);
        atomicAdd(&accy[l], pv.y);
    }
    __syncthreads();
    if (t < BSZ) {
        int node = (b << BSH) + t;
        if (node < N) {
            int2 ps = pi[node];  // self loop
            float d = dinv[node];
            float ax = (float)(ps.x + accx[t]) * (1.0f / S1);
            float ay = (float)(ps.y + accy[t]) * (1.0f / S1);
            float s0 = d * ax, s1 = d * ay;
            float u0 = sbe[0], u1 = sbe[1], u2 = sbe[2], u3 = sbe[3];
            float v0 = 0.f, v1 = 0.f, v2 = 0.f, v3 = 0.f;
            float w0 = 0.f, w1 = 0.f;
            #pragma unroll
            for (int jj = 0; jj < 16; jj++) {
                float hj = fmaf(s0, sW1[jj], fmaf(s1, sW1[16 + jj], sb1[jj]));
                u0 = fmaf(hj, sWr[4 * jj + 0], u0);
                u1 = fmaf(hj, sWr[4 * jj + 1], u1);
                u2 = fmaf(hj, sWr[4 * jj + 2], u2);
                u3 = fmaf(hj, sWr[4 * jj + 3], u3);
                v0 = fmaf(hj, sWc[4 * jj + 0], v0);
                v1 = fmaf(hj, sWc[4 * jj + 1], v1);
                v2 = fmaf(hj, sWc[4 * jj + 2], v2);
                v3 = fmaf(hj, sWc[4 * jj + 3], v3);
                w0 = fmaf(hj, sW2[2 * jj], w0);
                w1 = fmaf(hj, sW2[2 * jj + 1], w1);
            }
            U[node] = make_float4(u0, u1, u2, u3);
            V[node] = make_float4(v0, v1, v2, v3);
            float qx = w0 * d, qy = w1 * d;
            qi[node] = make_int2(__float2int_rn(qx * S2), __float2int_rn(qy * S2));
        }
    }
}

// ---- edge MLP: pure streaming, no atomics
__global__ void k_edge(const int* __restrict__ row, const int* __restrict__ col,
                       const float* __restrict__ ea, const float4* __restrict__ U,
                       const float4* __restrict__ V, const float* __restrict__ We,
                       float4* __restrict__ eout, int E) {
    __shared__ float sW16[4];
    int t = threadIdx.x;
    if (t < 4) sW16[t] = We[64 + t];   // We row 16 (edge_attr weights)
    __syncthreads();
    int e = blockIdx.x * BLK + t;
    if (e < E) {
        float4 u = U[row[e]];
        float4 v = V[col[e]];
        float av = ea[e];
        float a0 = u.x + fmaf(av, sW16[0], v.x);
        float a1 = u.y + fmaf(av, sW16[1], v.y);
        float a2 = u.z + fmaf(av, sW16[2], v.z);
        float a3 = u.w + fmaf(av, sW16[3], v.w);
        a0 = fmaxf(a0, 0.f); a1 = fmaxf(a1, 0.f);
        a2 = fmaxf(a2, 0.f); a3 = fmaxf(a3, 0.f);
        float m = fmaxf(fmaxf(a0, a1), fmaxf(a2, a3));
        float s = expf(a0 - m) + expf(a1 - m) + expf(a2 - m) + expf(a3 - m);
        float l = m + logf(s);
        eout[e] = make_float4(a0 - l, a1 - l, a2 - l, a3 - l);
    }
}

// ---- per-bucket conv2 aggregate (LDS int) -> node log_softmax
__global__ void k_nodeC(const unsigned* __restrict__ part, const int* __restrict__ gbase,
                        const float* __restrict__ dinv, const int2* __restrict__ qi,
                        const float* __restrict__ b2, float2* __restrict__ outn, int N) {
    __shared__ int accx[BSZ], accy[BSZ];
    int t = threadIdx.x;
    if (t < BSZ) { accx[t] = 0; accy[t] = 0; }
    __syncthreads();
    int b = blockIdx.x;
    int j0 = gbase[b], j1 = gbase[b + 1];
    for (int j = j0 + t; j < j1; j += BLK) {
        unsigned w = part[j];
        int2 qv = qi[w >> BSH];
        int l = (int)(w & (BSZ - 1));
        atomicAdd(&accx[l], qv.x);
        atomicAdd(&accy[l], qv.y);
    }
    __syncthreads();
    if (t < BSZ) {
        int node = (b << BSH) + t;
        if (node < N) {
            int2 qs = qi[node];  // self loop
            float d = dinv[node];
            float bx = (float)(qs.x + accx[t]) * (1.0f / S2);
            float by = (float)(qs.y + accy[t]) * (1.0f / S2);
            float o0 = fmaf(d, bx, b2[0]);
            float o1 = fmaf(d, by, b2[1]);
            float m = fmaxf(o0, o1);
            float l2 = m + logf(expf(o0 - m) + expf(o1 - m));
            outn[node] = make_float2(o0 - l2, o1 - l2);
        }
    }
}

extern "C" void kernel_launch(void* const* d_in, const int* in_sizes, int n_in,
                              void* d_out, int out_size, void* d_ws, size_t ws_size,
                              hipStream_t stream) {
    const float* x  = (const float*)d_in[0];
    const int*   ei = (const int*)d_in[1];
    const float* ea = (const float*)d_in[2];
    const float* W1 = (const float*)d_in[3];
    const float* b1 = (const float*)d_in[4];
    const float* We = (const float*)d_in[5];
    const float* be = (const float*)d_in[6];
    const float* W2 = (const float*)d_in[7];
    const float* b2 = (const float*)d_in[8];

    const int N = in_sizes[0] / 2;       // 100000
    const int E = in_sizes[2];           // 3200000
    const int* row = ei;
    const int* col = ei + E;
    const int NB  = (N + BSZ - 1) >> BSH;   // 782 buckets
    const int NCH = (E + CH - 1) / CH;      // 391 chunks

    float2* out_nodes = (float2*)d_out;                         // [N,2]
    float4* out_edges = (float4*)((float*)d_out + 2 * (size_t)N); // [E,4]

    // ws layout (bytes):
    char* ws = (char*)d_ws;
    int*      gcount  = (int*)     (ws + 0);         // NBMAX*4   = 4096
    int*      gbase   = (int*)     (ws + 4096);      // (NBMAX+1)*4, pad to 8192
    int*      gcursor = (int*)     (ws + 12288);     // NBMAX*4
    float*    dinv    = (float*)   (ws + 16384);     // N*4  = 400000
    int2*     pi      = (int2*)    (ws + 416384);    // N*8  = 800000
    int2*     qi      = (int2*)    (ws + 1216384);   // N*8
    float4*   U       = (float4*)  (ws + 2016384);   // N*16 = 1600000
    float4*   V       = (float4*)  (ws + 3616384);   // N*16
    unsigned* part    = (unsigned*)(ws + 5216384);   // E*4  = 12800000 -> 18016384 total

    hipMemsetAsync(gcount, 0, NBMAX * sizeof(int), stream);
    k_hist <<<NCH, BLK, 0, stream>>>(col, gcount, E, NB);
    k_scan <<<1,   BLK, 0, stream>>>(gcount, gbase, gcursor, NB);
    k_part <<<NCH, BLK, 0, stream>>>(row, col, gcursor, part, E, NB);
    k_nodeA<<<NB,  BLK, 0, stream>>>(part, gbase, (const float2*)x, dinv, pi, N);
    k_nodeB<<<NB,  BLK, 0, stream>>>(part, gbase, dinv, pi, W1, b1, W2, We, be, U, V, qi, N);
    k_edge <<<(E + BLK - 1) / BLK, BLK, 0, stream>>>(row, col, ea, U, V, We, out_edges, E);
    k_nodeC<<<NB,  BLK, 0, stream>>>(part, gbase, dinv, qi, b2, out_nodes, N);
}

// Round 6
// 248.990 us; speedup vs baseline: 3.6162x; 1.0480x over previous
//
#include <hip/hip_runtime.h>

// GCN 2-layer + edge MLP for SimpleModel_59545426592235.
// R6: (a) k_part flush no longer binary-searches run boundaries — bucket id
//     recorded at placement (ushort bid[CH] in LDS); (b) nodeB/nodeC
//     aggregate with ONE packed ds_add_u64 per edge instead of two b32
//     atomics: (x<<32)|(y+2^23); the bias keeps the low field non-negative
//     so no borrow crosses fields (|val|<=2^22, deg<=256 -> low sum < 2^32),
//     unbiased afterwards with deg[node]*2^23. Fixed-point scales S1=2^18,
//     S2=2^16; quantization error ~1e-3*dinv << threshold. Deterministic.

#define BLK 256
#define CH 8192            // edges per partition chunk
#define BSH 7              // 128 nodes per bucket
#define BSZ 128
#define NBMAX 1024         // max buckets (N <= 131072)
#define S1 262144.0f       // 2^18 conv1 scale
#define S2 65536.0f        // 2^16 conv2 scale
#define BIAS 8388608       // 2^23 low-field bias

// ---- per-chunk LDS histogram of col buckets -> global bucket counts
__global__ void k_hist(const int* __restrict__ col, int* __restrict__ gcount,
                       int E, int NB) {
    __shared__ int hist[NBMAX];
    int t = threadIdx.x;
    for (int b = t; b < NB; b += BLK) hist[b] = 0;
    __syncthreads();
    int e0 = blockIdx.x * CH;
    int cnt = min(CH, E - e0);
    for (int k = t; k < cnt; k += BLK)
        atomicAdd(&hist[col[e0 + k] >> BSH], 1);
    __syncthreads();
    for (int b = t; b < NB; b += BLK) {
        int h = hist[b];
        if (h) atomicAdd(&gcount[b], h);
    }
}

// ---- exclusive scan of bucket counts -> gbase[NB+1]; gcursor = gbase
__global__ void k_scan(const int* __restrict__ gcount, int* __restrict__ gbase,
                       int* __restrict__ gcursor, int NB) {
    __shared__ int sa[NBMAX], sb[NBMAX];
    int t = threadIdx.x;
    for (int i = t; i < NBMAX; i += BLK) sa[i] = (i < NB) ? gcount[i] : 0;
    __syncthreads();
    int *src = sa, *dst = sb;
    for (int off = 1; off < NBMAX; off <<= 1) {
        for (int i = t; i < NBMAX; i += BLK)
            dst[i] = src[i] + ((i >= off) ? src[i - off] : 0);
        __syncthreads();
        int* tmp = src; src = dst; dst = tmp;
    }
    for (int i = t; i < NB; i += BLK) {
        int ex = src[i] - gcount[i];
        gbase[i] = ex;
        gcursor[i] = ex;
    }
    if (t == 0) gbase[NB] = src[NB - 1];
}

// ---- partition: LDS counting sort of each chunk, coalesced run flush
__global__ void k_part(const int* __restrict__ row, const int* __restrict__ col,
                       int* __restrict__ gcursor, unsigned* __restrict__ part,
                       int E, int NB) {
    __shared__ int sa[NBMAX], sb[NBMAX];
    __shared__ int hist[NBMAX], lstart[NBMAX], lcur[NBMAX], gb[NBMAX];
    __shared__ unsigned sbuf[CH];
    __shared__ unsigned short bid[CH];
    int t = threadIdx.x;
    int e0 = blockIdx.x * CH;
    int cnt = min(CH, E - e0);
    for (int b = t; b < NB; b += BLK) hist[b] = 0;
    __syncthreads();
    for (int k = t; k < cnt; k += BLK)
        atomicAdd(&hist[col[e0 + k] >> BSH], 1);
    __syncthreads();
    // exclusive scan hist -> lstart; init lcur; reserve global space
    for (int i = t; i < NBMAX; i += BLK) sa[i] = (i < NB) ? hist[i] : 0;
    __syncthreads();
    int *src = sa, *dst = sb;
    for (int off = 1; off < NBMAX; off <<= 1) {
        for (int i = t; i < NBMAX; i += BLK)
            dst[i] = src[i] + ((i >= off) ? src[i - off] : 0);
        __syncthreads();
        int* tmp = src; src = dst; dst = tmp;
    }
    for (int i = t; i < NB; i += BLK) {
        int h = hist[i];
        int ex = src[i] - h;
        lstart[i] = ex;
        lcur[i] = ex;
        gb[i] = h ? atomicAdd(&gcursor[i], h) : 0;
    }
    __syncthreads();
    // place chunk edges into LDS buffer grouped by bucket; record bucket id
    for (int k = t; k < cnt; k += BLK) {
        int e = e0 + k;
        int c = col[e], r = row[e];
        int b = c >> BSH;
        int off = atomicAdd(&lcur[b], 1);
        sbuf[off] = ((unsigned)r << BSH) | (unsigned)(c & (BSZ - 1));
        bid[off] = (unsigned short)b;
    }
    __syncthreads();
    // flush: run id read directly, destination contiguous within each run
    for (int j = t; j < cnt; j += BLK) {
        int b = bid[j];
        part[gb[b] + (j - lstart[b])] = sbuf[j];
    }
}

// ---- per-bucket degree count -> deg, dinv, pi = x * dinv (fixed point)
__global__ void k_nodeA(const unsigned* __restrict__ part, const int* __restrict__ gbase,
                        const float2* __restrict__ x2, float* __restrict__ dinv,
                        int* __restrict__ degi, int2* __restrict__ pi, int N) {
    __shared__ int cnt[BSZ];
    int t = threadIdx.x;
    if (t < BSZ) cnt[t] = 0;
    __syncthreads();
    int b = blockIdx.x;
    int j0 = gbase[b], j1 = gbase[b + 1];
    for (int j = j0 + t; j < j1; j += BLK)
        atomicAdd(&cnt[part[j] & (BSZ - 1)], 1);
    __syncthreads();
    if (t < BSZ) {
        int node = (b << BSH) + t;
        if (node < N) {
            int dg = cnt[t];
            degi[node] = dg;
            float d = rsqrtf((float)(dg + 1));   // +1 self loop
            dinv[node] = d;
            float2 xv = x2[node];
            pi[node] = make_int2(__float2int_rn(xv.x * d * S1),
                                 __float2int_rn(xv.y * d * S1));
        }
    }
}

// ---- per-bucket conv1 aggregate (packed u64 LDS) -> h -> U, V, qi
__global__ void k_nodeB(const unsigned* __restrict__ part, const int* __restrict__ gbase,
                        const float* __restrict__ dinv, const int* __restrict__ degi,
                        const int2* __restrict__ pi,
                        const float* __restrict__ W1, const float* __restrict__ b1,
                        const float* __restrict__ W2, const float* __restrict__ We,
                        const float* __restrict__ be,
                        float4* __restrict__ U, float4* __restrict__ V,
                        int2* __restrict__ qi, int N) {
    __shared__ unsigned long long acc[BSZ];
    __shared__ float sW1[32], sb1[16], sW2[32], sWr[64], sWc[64], sbe[4];
    int t = threadIdx.x;
    if (t < BSZ) acc[t] = 0ull;
    if (t < 32) sW1[t] = W1[t];
    else if (t < 64) sW2[t - 32] = W2[t - 32];
    else if (t < 80) sb1[t - 64] = b1[t - 64];
    else if (t < 144) sWr[t - 80] = We[t - 80];          // We rows 0..15
    else if (t < 208) sWc[t - 144] = We[68 + (t - 144)]; // We rows 17..32
    else if (t < 212) sbe[t - 208] = be[t - 208];
    __syncthreads();
    int b = blockIdx.x;
    int j0 = gbase[b], j1 = gbase[b + 1];
    for (int j = j0 + t; j < j1; j += BLK) {
        unsigned w = part[j];
        int2 pv = pi[w >> BSH];
        int l = (int)(w & (BSZ - 1));
        unsigned long long val =
            ((unsigned long long)(unsigned)pv.x << 32) | (unsigned)(pv.y + BIAS);
        atomicAdd(&acc[l], val);
    }
    __syncthreads();
    if (t < BSZ) {
        int node = (b << BSH) + t;
        if (node < N) {
            unsigned long long a = acc[t];
            int sx = (int)(unsigned)(a >> 32);
            long long sy = (long long)(unsigned)(a & 0xffffffffull)
                         - (long long)degi[node] * BIAS;
            int2 ps = pi[node];  // self loop
            float d = dinv[node];
            float ax = (float)(ps.x + (long long)sx) * (1.0f / S1);
            float ay = (float)(ps.y + sy) * (1.0f / S1);
            float s0 = d * ax, s1 = d * ay;
            float u0 = sbe[0], u1 = sbe[1], u2 = sbe[2], u3 = sbe[3];
            float v0 = 0.f, v1 = 0.f, v2 = 0.f, v3 = 0.f;
            float w0 = 0.f, w1 = 0.f;
            #pragma unroll
            for (int jj = 0; jj < 16; jj++) {
                float hj = fmaf(s0, sW1[jj], fmaf(s1, sW1[16 + jj], sb1[jj]));
                u0 = fmaf(hj, sWr[4 * jj + 0], u0);
                u1 = fmaf(hj, sWr[4 * jj + 1], u1);
                u2 = fmaf(hj, sWr[4 * jj + 2], u2);
                u3 = fmaf(hj, sWr[4 * jj + 3], u3);
                v0 = fmaf(hj, sWc[4 * jj + 0], v0);
                v1 = fmaf(hj, sWc[4 * jj + 1], v1);
                v2 = fmaf(hj, sWc[4 * jj + 2], v2);
                v3 = fmaf(hj, sWc[4 * jj + 3], v3);
                w0 = fmaf(hj, sW2[2 * jj], w0);
                w1 = fmaf(hj, sW2[2 * jj + 1], w1);
            }
            U[node] = make_float4(u0, u1, u2, u3);
            V[node] = make_float4(v0, v1, v2, v3);
            float qx = w0 * d, qy = w1 * d;
            qi[node] = make_int2(__float2int_rn(qx * S2), __float2int_rn(qy * S2));
        }
    }
}

// ---- edge MLP: pure streaming, no atomics
__global__ void k_edge(const int* __restrict__ row, const int* __restrict__ col,
                       const float* __restrict__ ea, const float4* __restrict__ U,
                       const float4* __restrict__ V, const float* __restrict__ We,
                       float4* __restrict__ eout, int E) {
    __shared__ float sW16[4];
    int t = threadIdx.x;
    if (t < 4) sW16[t] = We[64 + t];   // We row 16 (edge_attr weights)
    __syncthreads();
    int e = blockIdx.x * BLK + t;
    if (e < E) {
        float4 u = U[row[e]];
        float4 v = V[col[e]];
        float av = ea[e];
        float a0 = u.x + fmaf(av, sW16[0], v.x);
        float a1 = u.y + fmaf(av, sW16[1], v.y);
        float a2 = u.z + fmaf(av, sW16[2], v.z);
        float a3 = u.w + fmaf(av, sW16[3], v.w);
        a0 = fmaxf(a0, 0.f); a1 = fmaxf(a1, 0.f);
        a2 = fmaxf(a2, 0.f); a3 = fmaxf(a3, 0.f);
        float m = fmaxf(fmaxf(a0, a1), fmaxf(a2, a3));
        float s = expf(a0 - m) + expf(a1 - m) + expf(a2 - m) + expf(a3 - m);
        float l = m + logf(s);
        eout[e] = make_float4(a0 - l, a1 - l, a2 - l, a3 - l);
    }
}

// ---- per-bucket conv2 aggregate (packed u64 LDS) -> node log_softmax
__global__ void k_nodeC(const unsigned* __restrict__ part, const int* __restrict__ gbase,
                        const float* __restrict__ dinv, const int* __restrict__ degi,
                        const int2* __restrict__ qi,
                        const float* __restrict__ b2, float2* __restrict__ outn, int N) {
    __shared__ unsigned long long acc[BSZ];
    int t = threadIdx.x;
    if (t < BSZ) acc[t] = 0ull;
    __syncthreads();
    int b = blockIdx.x;
    int j0 = gbase[b], j1 = gbase[b + 1];
    for (int j = j0 + t; j < j1; j += BLK) {
        unsigned w = part[j];
        int2 qv = qi[w >> BSH];
        int l = (int)(w & (BSZ - 1));
        unsigned long long val =
            ((unsigned long long)(unsigned)qv.x << 32) | (unsigned)(qv.y + BIAS);
        atomicAdd(&acc[l], val);
    }
    __syncthreads();
    if (t < BSZ) {
        int node = (b << BSH) + t;
        if (node < N) {
            unsigned long long a = acc[t];
            int sx = (int)(unsigned)(a >> 32);
            long long sy = (long long)(unsigned)(a & 0xffffffffull)
                         - (long long)degi[node] * BIAS;
            int2 qs = qi[node];  // self loop
            float d = dinv[node];
            float bx = (float)(qs.x + (long long)sx) * (1.0f / S2);
            float by = (float)(qs.y + sy) * (1.0f / S2);
            float o0 = fmaf(d, bx, b2[0]);
            float o1 = fmaf(d, by, b2[1]);
            float m = fmaxf(o0, o1);
            float l2 = m + logf(expf(o0 - m) + expf(o1 - m));
            outn[node] = make_float2(o0 - l2, o1 - l2);
        }
    }
}

extern "C" void kernel_launch(void* const* d_in, const int* in_sizes, int n_in,
                              void* d_out, int out_size, void* d_ws, size_t ws_size,
                              hipStream_t stream) {
    const float* x  = (const float*)d_in[0];
    const int*   ei = (const int*)d_in[1];
    const float* ea = (const float*)d_in[2];
    const float* W1 = (const float*)d_in[3];
    const float* b1 = (const float*)d_in[4];
    const float* We = (const float*)d_in[5];
    const float* be = (const float*)d_in[6];
    const float* W2 = (const float*)d_in[7];
    const float* b2 = (const float*)d_in[8];

    const int N = in_sizes[0] / 2;       // 100000
    const int E = in_sizes[2];           // 3200000
    const int* row = ei;
    const int* col = ei + E;
    const int NB  = (N + BSZ - 1) >> BSH;   // 782 buckets
    const int NCH = (E + CH - 1) / CH;      // 391 chunks

    float2* out_nodes = (float2*)d_out;                           // [N,2]
    float4* out_edges = (float4*)((float*)d_out + 2 * (size_t)N); // [E,4]

    // ws layout (bytes):
    char* ws = (char*)d_ws;
    int*      gcount  = (int*)     (ws + 0);         // NBMAX*4
    int*      gbase   = (int*)     (ws + 4096);      // (NBMAX+1)*4 (pad)
    int*      gcursor = (int*)     (ws + 12288);     // NBMAX*4
    float*    dinv    = (float*)   (ws + 16384);     // N*4
    int*      degi    = (int*)     (ws + 416384);    // N*4
    int2*     pi      = (int2*)    (ws + 816384);    // N*8
    int2*     qi      = (int2*)    (ws + 1616384);   // N*8
    float4*   U       = (float4*)  (ws + 2416384);   // N*16
    float4*   V       = (float4*)  (ws + 4016384);   // N*16
    unsigned* part    = (unsigned*)(ws + 5616384);   // E*4 -> 18.4 MB total

    hipMemsetAsync(gcount, 0, NBMAX * sizeof(int), stream);
    k_hist <<<NCH, BLK, 0, stream>>>(col, gcount, E, NB);
    k_scan <<<1,   BLK, 0, stream>>>(gcount, gbase, gcursor, NB);
    k_part <<<NCH, BLK, 0, stream>>>(row, col, gcursor, part, E, NB);
    k_nodeA<<<NB,  BLK, 0, stream>>>(part, gbase, (const float2*)x, dinv, degi, pi, N);
    k_nodeB<<<NB,  BLK, 0, stream>>>(part, gbase, dinv, degi, pi, W1, b1, W2, We, be, U, V, qi, N);
    k_edge <<<(E + BLK - 1) / BLK, BLK, 0, stream>>>(row, col, ea, U, V, We, out_edges, E);
    k_nodeC<<<NB,  BLK, 0, stream>>>(part, gbase, dinv, degi, qi, b2, out_nodes, N);
}